// Round 1
// baseline (148.282 us; speedup 1.0000x reference)
//
#include <hip/hip_runtime.h>

typedef __bf16 bf16_t;
typedef __bf16 bf16x8 __attribute__((ext_vector_type(8)));
typedef float  f32x4  __attribute__((ext_vector_type(4)));

#define Ldim 2048
#define Ddim 256
#define MROWS 32

// Build frag-major (B-operand) bf16 copies of weight and input_weight.
// Frag element ((kt*16+nt)*64 + lane)*8 + j  =  W[k=kt*32+(lane>>4)*8+j][n=nt*16+(lane&15)]
__global__ void swz_kernel(const float* __restrict__ w,
                           const float* __restrict__ win,
                           bf16_t* __restrict__ wsw,
                           bf16_t* __restrict__ winsw) {
    int mat = blockIdx.x >> 3, kt = blockIdx.x & 7;
    const float* src = mat ? win : w;
    bf16_t*      dst = mat ? winsw : wsw;
    int ln = threadIdx.x & 63, g = threadIdx.x >> 6;
    int c = ln & 15, q = ln >> 4;
#pragma unroll
    for (int i = 0; i < 4; ++i) {
        int nt = g + 4 * i;
        bf16x8 v;
#pragma unroll
        for (int j = 0; j < 8; ++j)
            v[j] = (bf16_t)src[(kt * 32 + q * 8 + j) * Ddim + nt * 16 + c];
        *(bf16x8*)&dst[((kt * 16 + nt) * 64 + ln) * 8] = v;
    }
}

// MROWS=32 / 512 blocks / launch_bounds(256,2): 2 blocks per CU, 2 waves per SIMD.
// Total LDS traffic and MFMA count identical to the MROWS=64 version; the win is
// cross-block overlap of the barrier-serialized recurrence phases.
__global__ __launch_bounds__(256, 2)
void rnn_kernel(const float* __restrict__ x,
                const float* __restrict__ bias,
                const float* __restrict__ tau,
                const bf16x8* __restrict__ wsw,
                const bf16x8* __restrict__ winsw,
                float* __restrict__ out)
{
    // h A-fragments, bit-permuted so the C-layout scatter is bank-conflict-free:
    // chunk (mt,kt) base = (mt*8+kt)*1024 B; element (lane', j) at
    // byte perm(lane')*16 + 2j, perm(lane' = qp<<4|q<<2|r) = r<<4|qp<<2|q.
    __shared__ bf16_t hbuf[2 * 8 * 512];   // 16384 B per block (2 blocks/CU -> 32 KiB)
    char* hb = (char*)hbuf;

    const int tid = threadIdx.x;
    const int w   = tid >> 6;   // wave: owns n-cols [64w, 64w+64)
    const int ln  = tid & 63;
    const int c   = ln & 15;
    const int q   = ln >> 4;
    const int blk = blockIdx.x;
    const int bb  = blk >> 6;             // batch
    const int l0  = (blk & 63) * MROWS;   // first output row within batch

    int   ncol[4];
    float itau[4];
#pragma unroll
    for (int nl = 0; nl < 4; ++nl) {
        ncol[nl] = (4 * w + nl) * 16 + c;
        itau[nl] = 1.0f / tau[ncol[nl]];
    }

    // ------------- phase 1: au = X_window @ W_in + bias (C layout) -------------
    f32x4 au[3][4];
#pragma unroll
    for (int nl = 0; nl < 4; ++nl) {
        float bv = bias[ncol[nl]];
#pragma unroll
        for (int mt = 0; mt < 3; ++mt) {
            f32x4 t = {bv, bv, bv, bv};
            au[mt][nl] = t;
        }
    }

    const float* xb = x + (long)bb * (Ldim * Ddim);
    const f32x4 zf = {0.f, 0.f, 0.f, 0.f};

    auto loadX = [&](f32x4 (&buf)[3][2], int kt) {
#pragma unroll
        for (int mt = 0; mt < 3; ++mt) {
            int  lrow = l0 - 7 + mt * 16 + c;
            bool ok   = (lrow >= 0) && (lrow < Ldim);
            const f32x4* p = (const f32x4*)(xb + (long)lrow * Ddim + kt * 32 + q * 8);
            buf[mt][0] = ok ? p[0] : zf;
            buf[mt][1] = ok ? p[1] : zf;
        }
    };
    auto loadW = [&](bf16x8 (&wb)[4], int kt) {
#pragma unroll
        for (int nl = 0; nl < 4; ++nl)
            wb[nl] = winsw[(kt * 16 + 4 * w + nl) * 64 + ln];
    };
    auto step1 = [&](const f32x4 (&buf)[3][2], const bf16x8 (&wb)[4]) {
        bf16x8 aF[3];
#pragma unroll
        for (int mt = 0; mt < 3; ++mt)
#pragma unroll
            for (int jj = 0; jj < 4; ++jj) {
                aF[mt][jj]     = (bf16_t)buf[mt][0][jj];
                aF[mt][jj + 4] = (bf16_t)buf[mt][1][jj];
            }
#pragma unroll
        for (int nl = 0; nl < 4; ++nl)
#pragma unroll
            for (int mt = 0; mt < 3; ++mt)
                au[mt][nl] = __builtin_amdgcn_mfma_f32_16x16x32_bf16(
                    aF[mt], wb[nl], au[mt][nl], 0, 0, 0);
    };

    {
        f32x4  x0[3][2], x1[3][2];
        bf16x8 w0[4], w1[4];
        loadX(x0, 0); loadW(w0, 0);
#pragma unroll 1
        for (int kk = 0; kk < 4; ++kk) {
            loadX(x1, 2 * kk + 1); loadW(w1, 2 * kk + 1);
            step1(x0, w0);
            if (kk < 3) { loadX(x0, 2 * kk + 2); loadW(w0, 2 * kk + 2); }
            step1(x1, w1);
        }
    }

    // ------------- phase 2: 8-step recurrence -------------
    bf16x8 bfr[8][4];   // W B-fragments, register resident (128 VGPRs)
#pragma unroll
    for (int kt = 0; kt < 8; ++kt)
#pragma unroll
        for (int nl = 0; nl < 4; ++nl)
            bfr[kt][nl] = wsw[(kt * 16 + 4 * w + nl) * 64 + ln];

    // per-lane scatter byte offsets (t-invariant)
    int offn[4];
#pragma unroll
    for (int nl = 0; nl < 4; ++nl) {
        int kk = ncol[nl];
        offn[nl] = (kk >> 5) * 1024 + ((kk >> 3) & 3) * 64 + q * 16 + (kk & 7) * 2;
    }
    const int permln = (((ln & 3) << 4) | ((ln >> 4) << 2) | ((ln >> 2) & 3)) * 16;
    const int sl     = (ln + 16) & 63;

    f32x4 h[2][4];   // h in C-layout fp32 (rows l0..l0+31)
#pragma unroll
    for (int mt = 0; mt < 2; ++mt)
#pragma unroll
        for (int nl = 0; nl < 4; ++nl)
#pragma unroll
            for (int r = 0; r < 4; ++r)
                h[mt][nl][r] = itau[nl] * fmaxf(au[mt][nl][r], 0.0f);

#pragma unroll 1
    for (int t = 1; t < 8; ++t) {
        // shift au down one row: au[r] <- au[r+1], au[3] <- next quad's (or next tile's) row 0
#pragma unroll
        for (int nl = 0; nl < 4; ++nl) {
            float a[3];
#pragma unroll
            for (int mt = 0; mt < 3; ++mt) a[mt] = __shfl(au[mt][nl][0], sl);
#pragma unroll
            for (int mt = 0; mt < 3; ++mt) {
                float n3 = (q < 3) ? a[mt] : (mt < 2 ? a[mt + 1] : a[mt]);
                f32x4 o = au[mt][nl];
                f32x4 s = {o[1], o[2], o[3], n3};
                au[mt][nl] = s;
            }
        }
        // scatter h (C-layout) -> hbuf (bf16 A-fragments), conflict-free layout
#pragma unroll
        for (int mt = 0; mt < 2; ++mt)
#pragma unroll
            for (int nl = 0; nl < 4; ++nl)
#pragma unroll
                for (int r = 0; r < 4; ++r)
                    *(bf16_t*)(hb + mt * 8192 + r * 256 + offn[nl]) =
                        (bf16_t)h[mt][nl][r];
        __syncthreads();
        // per-mt accumulator split keeps live acc at 16 VGPRs (fits 256-VGPR budget)
#pragma unroll
        for (int mt = 0; mt < 2; ++mt) {
            f32x4 acc[4];
#pragma unroll
            for (int nl = 0; nl < 4; ++nl) acc[nl] = au[mt][nl];
#pragma unroll
            for (int kt = 0; kt < 8; ++kt) {
                bf16x8 aF = *(const bf16x8*)(hb + (mt * 8 + kt) * 1024 + permln);
#pragma unroll
                for (int nl = 0; nl < 4; ++nl)
                    acc[nl] = __builtin_amdgcn_mfma_f32_16x16x32_bf16(
                        aF, bfr[kt][nl], acc[nl], 0, 0, 0);
            }
#pragma unroll
            for (int nl = 0; nl < 4; ++nl)
#pragma unroll
                for (int r = 0; r < 4; ++r) {
                    float hh = h[mt][nl][r];
                    float s  = fmaxf(acc[nl][r], 0.0f);
                    h[mt][nl][r] = hh + itau[nl] * (s - hh);
                }
        }
        __syncthreads();   // reads done before next iter's scatter
    }

    // ------------- epilogue -------------
    float* ob = out + ((long)bb * Ldim + l0) * Ddim;
#pragma unroll
    for (int mt = 0; mt < 2; ++mt)
#pragma unroll
        for (int nl = 0; nl < 4; ++nl)
#pragma unroll
            for (int r = 0; r < 4; ++r)
                ob[(mt * 16 + 4 * q + r) * Ddim + ncol[nl]] = h[mt][nl][r];
}

extern "C" void kernel_launch(void* const* d_in, const int* in_sizes, int n_in,
                              void* d_out, int out_size, void* d_ws, size_t ws_size,
                              hipStream_t stream) {
    const float* x            = (const float*)d_in[0];
    const float* weight       = (const float*)d_in[1];
    const float* input_weight = (const float*)d_in[2];
    const float* bias         = (const float*)d_in[3];
    const float* tau          = (const float*)d_in[4];
    (void)in_sizes; (void)n_in; (void)out_size; (void)ws_size;

    bf16_t* wsw   = (bf16_t*)d_ws;
    bf16_t* winsw = wsw + 65536;

    swz_kernel<<<16, 256, 0, stream>>>(weight, input_weight, wsw, winsw);
    rnn_kernel<<<512, 256, 0, stream>>>(x, bias, tau,
                                        (const bf16x8*)wsw, (const bf16x8*)winsw,
                                        (float*)d_out);
}

// Round 2
// 115.274 us; speedup vs baseline: 1.2863x; 1.2863x over previous
//
#include <hip/hip_runtime.h>

typedef __bf16 bf16_t;
typedef __bf16 bf16x8 __attribute__((ext_vector_type(8)));
typedef float  f32x4  __attribute__((ext_vector_type(4)));

#define Ldim 2048
#define Ddim 256
#define MROWS 64

// Build frag-major (B-operand) bf16 copies of weight and input_weight.
// Frag element ((kt*16+nt)*64 + lane)*8 + j  =  W[k=kt*32+(lane>>4)*8+j][n=nt*16+(lane&15)]
__global__ void swz_kernel(const float* __restrict__ w,
                           const float* __restrict__ win,
                           bf16_t* __restrict__ wsw,
                           bf16_t* __restrict__ winsw) {
    int mat = blockIdx.x >> 3, kt = blockIdx.x & 7;
    const float* src = mat ? win : w;
    bf16_t*      dst = mat ? winsw : wsw;
    int ln = threadIdx.x & 63, g = threadIdx.x >> 6;
    int c = ln & 15, q = ln >> 4;
#pragma unroll
    for (int i = 0; i < 4; ++i) {
        int nt = g + 4 * i;
        bf16x8 v;
#pragma unroll
        for (int j = 0; j < 8; ++j)
            v[j] = (bf16_t)src[(kt * 32 + q * 8 + j) * Ddim + nt * 16 + c];
        *(bf16x8*)&dst[((kt * 16 + nt) * 64 + ln) * 8] = v;
    }
}

// 8 waves/block (512 thr), each wave owns 2 n-col tiles (32 cols). MROWS=64,
// 256 blocks = 1 block/CU = 8 waves/CU = 2 waves/SIMD. Per-wave regs ~170
// (bfr 64 + au 40 + h 32 + misc) -> fits the 256-reg 2-wave budget, NO SPILL
// (round-1's 2-block version spilled ~117 MB of scratch; that was the regression).
__global__ __launch_bounds__(512, 2)
void rnn_kernel(const float* __restrict__ x,
                const float* __restrict__ bias,
                const float* __restrict__ tau,
                const bf16x8* __restrict__ wsw,
                const bf16x8* __restrict__ winsw,
                float* __restrict__ out)
{
    // h A-fragments, bit-permuted so the C-layout scatter is bank-conflict-free:
    // chunk (mt,kt) base = (mt*8+kt)*1024 B; element (lane', j) at
    // byte perm(lane')*16 + 2j, perm(lane' = qp<<4|q<<2|r) = r<<4|qp<<2|q.
    __shared__ bf16_t hbuf[4 * 8 * 512];   // 32768 B
    char* hb = (char*)hbuf;

    const int tid = threadIdx.x;
    const int w   = tid >> 6;   // wave: owns n-cols [32w, 32w+32)
    const int ln  = tid & 63;
    const int c   = ln & 15;
    const int q   = ln >> 4;
    const int blk = blockIdx.x;
    const int bb  = blk >> 5;             // batch
    const int l0  = (blk & 31) * MROWS;   // first output row within batch

    int   ncol[2];
    float itau[2];
#pragma unroll
    for (int nl = 0; nl < 2; ++nl) {
        ncol[nl] = (2 * w + nl) * 16 + c;
        itau[nl] = 1.0f / tau[ncol[nl]];
    }

    // ------------- phase 1: au = X_window @ W_in + bias (C layout) -------------
    f32x4 au[5][2];
#pragma unroll
    for (int nl = 0; nl < 2; ++nl) {
        float bv = bias[ncol[nl]];
#pragma unroll
        for (int mt = 0; mt < 5; ++mt) {
            f32x4 t = {bv, bv, bv, bv};
            au[mt][nl] = t;
        }
    }

    const float* xb = x + (long)bb * (Ldim * Ddim);
    const f32x4 zf = {0.f, 0.f, 0.f, 0.f};

    auto loadX = [&](f32x4 (&buf)[5][2], int kt) {
#pragma unroll
        for (int mt = 0; mt < 5; ++mt) {
            int  lrow = l0 - 7 + mt * 16 + c;
            bool ok   = (lrow >= 0) && (lrow < Ldim);
            const f32x4* p = (const f32x4*)(xb + (long)lrow * Ddim + kt * 32 + q * 8);
            buf[mt][0] = ok ? p[0] : zf;
            buf[mt][1] = ok ? p[1] : zf;
        }
    };
    auto loadW = [&](bf16x8 (&wb)[2], int kt) {
#pragma unroll
        for (int nl = 0; nl < 2; ++nl)
            wb[nl] = winsw[(kt * 16 + 2 * w + nl) * 64 + ln];
    };
    auto step1 = [&](const f32x4 (&buf)[5][2], const bf16x8 (&wb)[2]) {
        bf16x8 aF[5];
#pragma unroll
        for (int mt = 0; mt < 5; ++mt)
#pragma unroll
            for (int jj = 0; jj < 4; ++jj) {
                aF[mt][jj]     = (bf16_t)buf[mt][0][jj];
                aF[mt][jj + 4] = (bf16_t)buf[mt][1][jj];
            }
#pragma unroll
        for (int nl = 0; nl < 2; ++nl)
#pragma unroll
            for (int mt = 0; mt < 5; ++mt)
                au[mt][nl] = __builtin_amdgcn_mfma_f32_16x16x32_bf16(
                    aF[mt], wb[nl], au[mt][nl], 0, 0, 0);
    };

    {
        f32x4  x0[5][2], x1[5][2];
        bf16x8 w0[2], w1[2];
        loadX(x0, 0); loadW(w0, 0);
#pragma unroll 1
        for (int kk = 0; kk < 4; ++kk) {
            loadX(x1, 2 * kk + 1); loadW(w1, 2 * kk + 1);
            step1(x0, w0);
            if (kk < 3) { loadX(x0, 2 * kk + 2); loadW(w0, 2 * kk + 2); }
            step1(x1, w1);
        }
    }

    // ------------- phase 2: 8-step recurrence -------------
    bf16x8 bfr[8][2];   // W B-fragments, register resident (64 VGPRs)
#pragma unroll
    for (int kt = 0; kt < 8; ++kt)
#pragma unroll
        for (int nl = 0; nl < 2; ++nl)
            bfr[kt][nl] = wsw[(kt * 16 + 2 * w + nl) * 64 + ln];

    // per-lane scatter byte offsets (t-invariant)
    int offn[2];
#pragma unroll
    for (int nl = 0; nl < 2; ++nl) {
        int kk = ncol[nl];
        offn[nl] = (kk >> 5) * 1024 + ((kk >> 3) & 3) * 64 + q * 16 + (kk & 7) * 2;
    }
    const int permln = (((ln & 3) << 4) | ((ln >> 4) << 2) | ((ln >> 2) & 3)) * 16;
    const int sl     = (ln + 16) & 63;

    f32x4 h[4][2];   // h in C-layout fp32
#pragma unroll
    for (int mt = 0; mt < 4; ++mt)
#pragma unroll
        for (int nl = 0; nl < 2; ++nl)
#pragma unroll
            for (int r = 0; r < 4; ++r)
                h[mt][nl][r] = itau[nl] * fmaxf(au[mt][nl][r], 0.0f);

#pragma unroll 1
    for (int t = 1; t < 8; ++t) {
        // shift au down one row: au[r] <- au[r+1], au[3] <- next quad's (or next tile's) row 0
#pragma unroll
        for (int nl = 0; nl < 2; ++nl) {
            float a[5];
#pragma unroll
            for (int mt = 0; mt < 5; ++mt) a[mt] = __shfl(au[mt][nl][0], sl);
#pragma unroll
            for (int mt = 0; mt < 5; ++mt) {
                float n3 = (q < 3) ? a[mt] : (mt < 4 ? a[mt + 1] : a[mt]);
                f32x4 o = au[mt][nl];
                f32x4 s = {o[1], o[2], o[3], n3};
                au[mt][nl] = s;
            }
        }
        // scatter h (C-layout) -> hbuf (bf16 A-fragments), conflict-free layout
#pragma unroll
        for (int mt = 0; mt < 4; ++mt)
#pragma unroll
            for (int nl = 0; nl < 2; ++nl)
#pragma unroll
                for (int r = 0; r < 4; ++r)
                    *(bf16_t*)(hb + mt * 8192 + r * 256 + offn[nl]) =
                        (bf16_t)h[mt][nl][r];
        __syncthreads();
        // per-mt accumulator split keeps live acc small; aF reused across both nl
#pragma unroll
        for (int mt = 0; mt < 4; ++mt) {
            f32x4 acc[2];
#pragma unroll
            for (int nl = 0; nl < 2; ++nl) acc[nl] = au[mt][nl];
#pragma unroll
            for (int kt = 0; kt < 8; ++kt) {
                bf16x8 aF = *(const bf16x8*)(hb + (mt * 8 + kt) * 1024 + permln);
#pragma unroll
                for (int nl = 0; nl < 2; ++nl)
                    acc[nl] = __builtin_amdgcn_mfma_f32_16x16x32_bf16(
                        aF, bfr[kt][nl], acc[nl], 0, 0, 0);
            }
#pragma unroll
            for (int nl = 0; nl < 2; ++nl)
#pragma unroll
                for (int r = 0; r < 4; ++r) {
                    float hh = h[mt][nl][r];
                    float s  = fmaxf(acc[nl][r], 0.0f);
                    h[mt][nl][r] = hh + itau[nl] * (s - hh);
                }
        }
        __syncthreads();   // reads done before next iter's scatter
    }

    // ------------- epilogue -------------
    float* ob = out + ((long)bb * Ldim + l0) * Ddim;
#pragma unroll
    for (int mt = 0; mt < 4; ++mt)
#pragma unroll
        for (int nl = 0; nl < 2; ++nl)
#pragma unroll
            for (int r = 0; r < 4; ++r)
                ob[(mt * 16 + 4 * q + r) * Ddim + ncol[nl]] = h[mt][nl][r];
}

extern "C" void kernel_launch(void* const* d_in, const int* in_sizes, int n_in,
                              void* d_out, int out_size, void* d_ws, size_t ws_size,
                              hipStream_t stream) {
    const float* x            = (const float*)d_in[0];
    const float* weight       = (const float*)d_in[1];
    const float* input_weight = (const float*)d_in[2];
    const float* bias         = (const float*)d_in[3];
    const float* tau          = (const float*)d_in[4];
    (void)in_sizes; (void)n_in; (void)out_size; (void)ws_size;

    bf16_t* wsw   = (bf16_t*)d_ws;
    bf16_t* winsw = wsw + 65536;

    swz_kernel<<<16, 256, 0, stream>>>(weight, input_weight, wsw, winsw);
    rnn_kernel<<<256, 512, 0, stream>>>(x, bias, tau,
                                        (const bf16x8*)wsw, (const bf16x8*)winsw,
                                        (float*)d_out);
}

// Round 3
// 108.197 us; speedup vs baseline: 1.3705x; 1.0654x over previous
//
#include <hip/hip_runtime.h>

typedef __bf16 bf16_t;
typedef __bf16 bf16x8 __attribute__((ext_vector_type(8)));
typedef float  f32x4  __attribute__((ext_vector_type(4)));

#define Ldim 2048
#define Ddim 256

// Build frag-major (B-operand) bf16 copies of weight and input_weight.
// Frag element ((kt*16+nt)*64 + lane)*8 + j  =  W[k=kt*32+(lane>>4)*8+j][n=nt*16+(lane&15)]
__global__ void swz_kernel(const float* __restrict__ w,
                           const float* __restrict__ win,
                           bf16_t* __restrict__ wsw,
                           bf16_t* __restrict__ winsw) {
    int mat = blockIdx.x >> 3, kt = blockIdx.x & 7;
    const float* src = mat ? win : w;
    bf16_t*      dst = mat ? winsw : wsw;
    int ln = threadIdx.x & 63, g = threadIdx.x >> 6;
    int c = ln & 15, q = ln >> 4;
#pragma unroll
    for (int i = 0; i < 4; ++i) {
        int nt = g + 4 * i;
        bf16x8 v;
#pragma unroll
        for (int j = 0; j < 8; ++j)
            v[j] = (bf16_t)src[(kt * 32 + q * 8 + j) * Ddim + nt * 16 + c];
        *(bf16x8*)&dst[((kt * 16 + nt) * 64 + ln) * 8] = v;
    }
}

#define AU_STRIDE 258   // f32 units; 4-row step = 1032 B = 8 banks -> 2-way (free)
#define AU_ROWS   40
#define AU_BYTES  (AU_ROWS * AU_STRIDE * 4)      // 41280
#define HBUF_BYTES 65536                          // [2 buf][2 grp][2 mt][8 kt][1024]
#define LDS_TOTAL (HBUF_BYTES + 2 * AU_BYTES)     // 148096 <= 160 KiB

extern __shared__ char ldsmem[];

// 512 thr = 2 groups x 4 waves. Each group: independent 32-row window, nl=4
// (each gather b128 feeds 4 MFMAs). 2 waves/SIMD, 1 block/CU (148 KB LDS).
// au (= X*Win + bias window) lives in LDS -> no shuffle-shift, fewer regs.
__global__ __launch_bounds__(512, 2)
void rnn_kernel(const float* __restrict__ x,
                const float* __restrict__ bias,
                const float* __restrict__ tau,
                const bf16x8* __restrict__ wsw,
                const bf16x8* __restrict__ winsw,
                float* __restrict__ out)
{
    char*  hb      = ldsmem;                       // h A-frag double buffer
    float* auf_all = (float*)(ldsmem + HBUF_BYTES);

    const int tid = threadIdx.x;
    const int w   = tid >> 6;
    const int ln  = tid & 63;
    const int c   = ln & 15;
    const int q   = ln >> 4;
    const int grp = w >> 2;          // 0/1: independent row-window
    const int w4  = w & 3;           // wave within group: owns n-cols [64*w4, +64)
    const int tile = blockIdx.x * 2 + grp;   // 512 tiles of 32 rows
    const int bb  = tile >> 6;               // batch
    const int l0  = (tile & 63) * 32;        // first output row within batch

    float* auf = auf_all + grp * (AU_ROWS * AU_STRIDE);

    int   ncol[4];
    float itau[4];
#pragma unroll
    for (int nl = 0; nl < 4; ++nl) {
        ncol[nl] = (w4 * 4 + nl) * 16 + c;
        itau[nl] = 1.0f / tau[ncol[nl]];
    }

    // ------------- phase 1: au = X_window @ W_in + bias (C layout) -------------
    // rows covered: l0-7 + [0,48)  (39 used: window rows 0..38)
    f32x4 au[3][4];
#pragma unroll
    for (int nl = 0; nl < 4; ++nl) {
        float bv = bias[ncol[nl]];
#pragma unroll
        for (int mt = 0; mt < 3; ++mt) {
            f32x4 t = {bv, bv, bv, bv};
            au[mt][nl] = t;
        }
    }

    const float* xb = x + (long)bb * (Ldim * Ddim);
    const f32x4 zf = {0.f, 0.f, 0.f, 0.f};

    auto loadX = [&](f32x4 (&buf)[3][2], int kt) {
#pragma unroll
        for (int mt = 0; mt < 3; ++mt) {
            int  lrow = l0 - 7 + mt * 16 + c;
            bool ok   = (lrow >= 0) && (lrow < Ldim);
            const f32x4* p = (const f32x4*)(xb + (long)lrow * Ddim + kt * 32 + q * 8);
            buf[mt][0] = ok ? p[0] : zf;
            buf[mt][1] = ok ? p[1] : zf;
        }
    };
    auto loadW = [&](bf16x8 (&wb)[4], int kt) {
#pragma unroll
        for (int nl = 0; nl < 4; ++nl)
            wb[nl] = winsw[(kt * 16 + 4 * w4 + nl) * 64 + ln];
    };
    auto step1 = [&](const f32x4 (&buf)[3][2], const bf16x8 (&wb)[4]) {
        bf16x8 aF[3];
#pragma unroll
        for (int mt = 0; mt < 3; ++mt)
#pragma unroll
            for (int jj = 0; jj < 4; ++jj) {
                aF[mt][jj]     = (bf16_t)buf[mt][0][jj];
                aF[mt][jj + 4] = (bf16_t)buf[mt][1][jj];
            }
#pragma unroll
        for (int nl = 0; nl < 4; ++nl)
#pragma unroll
            for (int mt = 0; mt < 3; ++mt)
                au[mt][nl] = __builtin_amdgcn_mfma_f32_16x16x32_bf16(
                    aF[mt], wb[nl], au[mt][nl], 0, 0, 0);
    };

    {
        f32x4  x0[3][2], x1[3][2];
        bf16x8 w0[4], w1[4];
        loadX(x0, 0); loadW(w0, 0);
#pragma unroll 1
        for (int kk = 0; kk < 4; ++kk) {
            loadX(x1, 2 * kk + 1); loadW(w1, 2 * kk + 1);
            step1(x0, w0);
            if (kk < 3) { loadX(x0, 2 * kk + 2); loadW(w0, 2 * kk + 2); }
            step1(x1, w1);
        }
    }

    // spill au -> LDS (wave-private column stripe; rows 0..38 used)
#pragma unroll
    for (int mt = 0; mt < 3; ++mt)
#pragma unroll
        for (int nl = 0; nl < 4; ++nl)
#pragma unroll
            for (int r = 0; r < 4; ++r) {
                int row = mt * 16 + q * 4 + r;
                if (row < 39)
                    auf[row * AU_STRIDE + ncol[nl]] = au[mt][nl][r];
            }

    // h init: h_1 = itau * relu(u at window row m), m = mt*16 + q*4 + r (0..31)
    f32x4 h[2][4];
#pragma unroll
    for (int mt = 0; mt < 2; ++mt)
#pragma unroll
        for (int nl = 0; nl < 4; ++nl)
#pragma unroll
            for (int r = 0; r < 4; ++r)
                h[mt][nl][r] = itau[nl] * fmaxf(au[mt][nl][r], 0.0f);

    // ------------- phase 2: 7 more recurrence steps -------------
    bf16x8 bfr[8][4];   // W B-fragments, register resident (128 VGPRs)
#pragma unroll
    for (int kt = 0; kt < 8; ++kt)
#pragma unroll
        for (int nl = 0; nl < 4; ++nl)
            bfr[kt][nl] = wsw[(kt * 16 + 4 * w4 + nl) * 64 + ln];

    // per-lane scatter byte offsets (t-invariant), bank-conflict-free perm
    int offn[4];
#pragma unroll
    for (int nl = 0; nl < 4; ++nl) {
        int kk = ncol[nl];
        offn[nl] = (kk >> 5) * 1024 + ((kk >> 3) & 3) * 64 + q * 16 + (kk & 7) * 2;
    }
    const int permln = (((ln & 3) << 4) | ((ln >> 4) << 2) | ((ln >> 2) & 3)) * 16;

    char* hbg = hb + grp * 16384;

    // initial scatter of h into buf 0
#pragma unroll
    for (int mt = 0; mt < 2; ++mt)
#pragma unroll
        for (int nl = 0; nl < 4; ++nl)
#pragma unroll
            for (int r = 0; r < 4; ++r)
                *(bf16_t*)(hbg + mt * 8192 + r * 256 + offn[nl]) =
                    (bf16_t)h[mt][nl][r];
    __syncthreads();

    int cur = 0;
#pragma unroll 1
    for (int t = 1; t < 8; ++t) {
        char* pc = hbg + cur * 32768;
        char* pn = hbg + (cur ^ 1) * 32768;
        const float* urow = auf + (q * 4 + t) * AU_STRIDE;
#pragma unroll
        for (int mt = 0; mt < 2; ++mt) {
            f32x4 acc[4];
#pragma unroll
            for (int nl = 0; nl < 4; ++nl) {
                f32x4 a;
#pragma unroll
                for (int r = 0; r < 4; ++r)
                    a[r] = urow[(mt * 16 + r) * AU_STRIDE + ncol[nl]];
                acc[nl] = a;
            }
            __builtin_amdgcn_s_setprio(1);
#pragma unroll
            for (int kt = 0; kt < 8; ++kt) {
                bf16x8 aF = *(const bf16x8*)(pc + (mt * 8 + kt) * 1024 + permln);
#pragma unroll
                for (int nl = 0; nl < 4; ++nl)
                    acc[nl] = __builtin_amdgcn_mfma_f32_16x16x32_bf16(
                        aF, bfr[kt][nl], acc[nl], 0, 0, 0);
            }
            __builtin_amdgcn_s_setprio(0);
#pragma unroll
            for (int nl = 0; nl < 4; ++nl)
#pragma unroll
                for (int r = 0; r < 4; ++r) {
                    float hh = h[mt][nl][r];
                    float s  = fmaxf(acc[nl][r], 0.0f);
                    h[mt][nl][r] = hh + itau[nl] * (s - hh);
                }
            if (t < 7) {
#pragma unroll
                for (int nl = 0; nl < 4; ++nl)
#pragma unroll
                    for (int r = 0; r < 4; ++r)
                        *(bf16_t*)(pn + mt * 8192 + r * 256 + offn[nl]) =
                            (bf16_t)h[mt][nl][r];
            }
        }
        if (t < 7) __syncthreads();
        cur ^= 1;
    }

    // ------------- epilogue -------------
    float* ob = out + ((long)bb * Ldim + l0) * Ddim;
#pragma unroll
    for (int mt = 0; mt < 2; ++mt)
#pragma unroll
        for (int nl = 0; nl < 4; ++nl)
#pragma unroll
            for (int r = 0; r < 4; ++r)
                ob[(mt * 16 + 4 * q + r) * Ddim + ncol[nl]] = h[mt][nl][r];
}

extern "C" void kernel_launch(void* const* d_in, const int* in_sizes, int n_in,
                              void* d_out, int out_size, void* d_ws, size_t ws_size,
                              hipStream_t stream) {
    const float* x            = (const float*)d_in[0];
    const float* weight       = (const float*)d_in[1];
    const float* input_weight = (const float*)d_in[2];
    const float* bias         = (const float*)d_in[3];
    const float* tau          = (const float*)d_in[4];
    (void)in_sizes; (void)n_in; (void)out_size; (void)ws_size;

    bf16_t* wsw   = (bf16_t*)d_ws;
    bf16_t* winsw = wsw + 65536;

    static bool attr_set = false;
    if (!attr_set) {
        (void)hipFuncSetAttribute((const void*)rnn_kernel,
                                  hipFuncAttributeMaxDynamicSharedMemorySize,
                                  LDS_TOTAL);
        attr_set = true;
    }

    swz_kernel<<<16, 256, 0, stream>>>(weight, input_weight, wsw, winsw);
    rnn_kernel<<<256, 512, LDS_TOTAL, stream>>>(x, bias, tau,
                                                (const bf16x8*)wsw,
                                                (const bf16x8*)winsw,
                                                (float*)d_out);
}

// Round 4
// 107.395 us; speedup vs baseline: 1.3807x; 1.0075x over previous
//
#include <hip/hip_runtime.h>

typedef __bf16 bf16_t;
typedef __bf16 bf16x8 __attribute__((ext_vector_type(8)));
typedef float  f32x4  __attribute__((ext_vector_type(4)));

#define Ldim 2048
#define Ddim 256

// Build frag-major (B-operand) bf16 copies of weight and input_weight.
// Frag element ((kt*16+nt)*64 + lane)*8 + j  =  W[k=kt*32+(lane>>4)*8+j][n=nt*16+(lane&15)]
__global__ void swz_kernel(const float* __restrict__ w,
                           const float* __restrict__ win,
                           bf16_t* __restrict__ wsw,
                           bf16_t* __restrict__ winsw) {
    int mat = blockIdx.x >> 3, kt = blockIdx.x & 7;
    const float* src = mat ? win : w;
    bf16_t*      dst = mat ? winsw : wsw;
    int ln = threadIdx.x & 63, g = threadIdx.x >> 6;
    int c = ln & 15, q = ln >> 4;
#pragma unroll
    for (int i = 0; i < 4; ++i) {
        int nt = g + 4 * i;
        bf16x8 v;
#pragma unroll
        for (int j = 0; j < 8; ++j)
            v[j] = (bf16_t)src[(kt * 32 + q * 8 + j) * Ddim + nt * 16 + c];
        *(bf16x8*)&dst[((kt * 16 + nt) * 64 + ln) * 8] = v;
    }
}

#define AU_STRIDE 258   // f32 units; 4-row step = 1032 B -> 2-way bank alias (free)
#define AU_ROWS   40
#define AU_BYTES  (AU_ROWS * AU_STRIDE * 4)       // 41280
#define HBUF_BYTES 32768                          // [2 buf][2 mt][8 kt][1024]
#define LDS_TOTAL (HBUF_BYTES + AU_BYTES)         // 74048 -> 2 blocks/CU

extern __shared__ char ldsmem[];

// 256 thr = 4 waves, each wave nl=4 (gather b128 feeds 4 MFMAs). 32-row tile,
// grid 512 = 2 blocks/CU = 2 waves/SIMD from INDEPENDENT blocks: private
// barriers decorrelate the per-step stall windows (round-3's block-wide
// __syncthreads kept both co-resident waves in lockstep -> no overlap).
// au in LDS (round-3) keeps phase-2 regs ~220 incl AGPR -> no spill at (256,2).
__global__ __launch_bounds__(256, 2)
void rnn_kernel(const float* __restrict__ x,
                const float* __restrict__ bias,
                const float* __restrict__ tau,
                const bf16x8* __restrict__ wsw,
                const bf16x8* __restrict__ winsw,
                float* __restrict__ out)
{
    char*  hb  = ldsmem;                       // h A-frag double buffer
    float* auf = (float*)(ldsmem + HBUF_BYTES);

    const int tid = threadIdx.x;
    const int w   = tid >> 6;        // wave: owns n-cols [64w, 64w+64)
    const int ln  = tid & 63;
    const int c   = ln & 15;
    const int q   = ln >> 4;
    const int tile = blockIdx.x;             // 512 tiles of 32 rows
    const int bb  = tile >> 6;               // batch
    const int l0  = (tile & 63) * 32;        // first output row within batch

    int   ncol[4];
    float itau[4];
#pragma unroll
    for (int nl = 0; nl < 4; ++nl) {
        ncol[nl] = (w * 4 + nl) * 16 + c;
        itau[nl] = 1.0f / tau[ncol[nl]];
    }

    // ------------- phase 1: au = X_window @ W_in + bias (C layout) -------------
    // rows covered: l0-7 + [0,48)  (39 used: window rows 0..38)
    f32x4 au[3][4];
#pragma unroll
    for (int nl = 0; nl < 4; ++nl) {
        float bv = bias[ncol[nl]];
#pragma unroll
        for (int mt = 0; mt < 3; ++mt) {
            f32x4 t = {bv, bv, bv, bv};
            au[mt][nl] = t;
        }
    }

    const float* xb = x + (long)bb * (Ldim * Ddim);
    const f32x4 zf = {0.f, 0.f, 0.f, 0.f};

    auto loadX = [&](f32x4 (&buf)[3][2], int kt) {
#pragma unroll
        for (int mt = 0; mt < 3; ++mt) {
            int  lrow = l0 - 7 + mt * 16 + c;
            bool ok   = (lrow >= 0) && (lrow < Ldim);
            const f32x4* p = (const f32x4*)(xb + (long)lrow * Ddim + kt * 32 + q * 8);
            buf[mt][0] = ok ? p[0] : zf;
            buf[mt][1] = ok ? p[1] : zf;
        }
    };
    auto loadW = [&](bf16x8 (&wb)[4], int kt) {
#pragma unroll
        for (int nl = 0; nl < 4; ++nl)
            wb[nl] = winsw[(kt * 16 + 4 * w + nl) * 64 + ln];
    };
    auto step1 = [&](const f32x4 (&buf)[3][2], const bf16x8 (&wb)[4]) {
        bf16x8 aF[3];
#pragma unroll
        for (int mt = 0; mt < 3; ++mt)
#pragma unroll
            for (int jj = 0; jj < 4; ++jj) {
                aF[mt][jj]     = (bf16_t)buf[mt][0][jj];
                aF[mt][jj + 4] = (bf16_t)buf[mt][1][jj];
            }
#pragma unroll
        for (int nl = 0; nl < 4; ++nl)
#pragma unroll
            for (int mt = 0; mt < 3; ++mt)
                au[mt][nl] = __builtin_amdgcn_mfma_f32_16x16x32_bf16(
                    aF[mt], wb[nl], au[mt][nl], 0, 0, 0);
    };

    {
        f32x4  x0[3][2], x1[3][2];
        bf16x8 w0[4], w1[4];
        loadX(x0, 0); loadW(w0, 0);
#pragma unroll 1
        for (int kk = 0; kk < 4; ++kk) {
            loadX(x1, 2 * kk + 1); loadW(w1, 2 * kk + 1);
            step1(x0, w0);
            if (kk < 3) { loadX(x0, 2 * kk + 2); loadW(w0, 2 * kk + 2); }
            step1(x1, w1);
        }
    }

    // spill au -> LDS (wave-private column stripe; rows 0..38 used)
#pragma unroll
    for (int mt = 0; mt < 3; ++mt)
#pragma unroll
        for (int nl = 0; nl < 4; ++nl)
#pragma unroll
            for (int r = 0; r < 4; ++r) {
                int row = mt * 16 + q * 4 + r;
                if (row < 39)
                    auf[row * AU_STRIDE + ncol[nl]] = au[mt][nl][r];
            }

    // h init: h_1 = itau * relu(u at window row m), m = mt*16 + q*4 + r (0..31)
    f32x4 h[2][4];
#pragma unroll
    for (int mt = 0; mt < 2; ++mt)
#pragma unroll
        for (int nl = 0; nl < 4; ++nl)
#pragma unroll
            for (int r = 0; r < 4; ++r)
                h[mt][nl][r] = itau[nl] * fmaxf(au[mt][nl][r], 0.0f);

    // ------------- phase 2: 7 more recurrence steps -------------
    bf16x8 bfr[8][4];   // W B-fragments, register resident (128 VGPRs)
#pragma unroll
    for (int kt = 0; kt < 8; ++kt)
#pragma unroll
        for (int nl = 0; nl < 4; ++nl)
            bfr[kt][nl] = wsw[(kt * 16 + 4 * w + nl) * 64 + ln];

    // per-lane scatter byte offsets (t-invariant), bank-conflict-free perm
    int offn[4];
#pragma unroll
    for (int nl = 0; nl < 4; ++nl) {
        int kk = ncol[nl];
        offn[nl] = (kk >> 5) * 1024 + ((kk >> 3) & 3) * 64 + q * 16 + (kk & 7) * 2;
    }
    const int permln = (((ln & 3) << 4) | ((ln >> 4) << 2) | ((ln >> 2) & 3)) * 16;

    // initial scatter of h into buf 0
#pragma unroll
    for (int mt = 0; mt < 2; ++mt)
#pragma unroll
        for (int nl = 0; nl < 4; ++nl)
#pragma unroll
            for (int r = 0; r < 4; ++r)
                *(bf16_t*)(hb + mt * 8192 + r * 256 + offn[nl]) =
                    (bf16_t)h[mt][nl][r];
    __syncthreads();

    int cur = 0;
#pragma unroll 1
    for (int t = 1; t < 8; ++t) {
        char* pc = hb + cur * 16384;
        char* pn = hb + (cur ^ 1) * 16384;
        const float* urow = auf + (q * 4 + t) * AU_STRIDE;
#pragma unroll
        for (int mt = 0; mt < 2; ++mt) {
            f32x4 acc[4];
#pragma unroll
            for (int nl = 0; nl < 4; ++nl) {
                f32x4 a;
#pragma unroll
                for (int r = 0; r < 4; ++r)
                    a[r] = urow[(mt * 16 + r) * AU_STRIDE + ncol[nl]];
                acc[nl] = a;
            }
            __builtin_amdgcn_s_setprio(1);
#pragma unroll
            for (int kt = 0; kt < 8; ++kt) {
                bf16x8 aF = *(const bf16x8*)(pc + (mt * 8 + kt) * 1024 + permln);
#pragma unroll
                for (int nl = 0; nl < 4; ++nl)
                    acc[nl] = __builtin_amdgcn_mfma_f32_16x16x32_bf16(
                        aF, bfr[kt][nl], acc[nl], 0, 0, 0);
            }
            __builtin_amdgcn_s_setprio(0);
#pragma unroll
            for (int nl = 0; nl < 4; ++nl)
#pragma unroll
                for (int r = 0; r < 4; ++r) {
                    float hh = h[mt][nl][r];
                    float s  = fmaxf(acc[nl][r], 0.0f);
                    h[mt][nl][r] = hh + itau[nl] * (s - hh);
                }
            if (t < 7) {
#pragma unroll
                for (int nl = 0; nl < 4; ++nl)
#pragma unroll
                    for (int r = 0; r < 4; ++r)
                        *(bf16_t*)(pn + mt * 8192 + r * 256 + offn[nl]) =
                            (bf16_t)h[mt][nl][r];
            }
        }
        if (t < 7) __syncthreads();
        cur ^= 1;
    }

    // ------------- epilogue -------------
    float* ob = out + ((long)bb * Ldim + l0) * Ddim;
#pragma unroll
    for (int mt = 0; mt < 2; ++mt)
#pragma unroll
        for (int nl = 0; nl < 4; ++nl)
#pragma unroll
            for (int r = 0; r < 4; ++r)
                ob[(mt * 16 + 4 * q + r) * Ddim + ncol[nl]] = h[mt][nl][r];
}

extern "C" void kernel_launch(void* const* d_in, const int* in_sizes, int n_in,
                              void* d_out, int out_size, void* d_ws, size_t ws_size,
                              hipStream_t stream) {
    const float* x            = (const float*)d_in[0];
    const float* weight       = (const float*)d_in[1];
    const float* input_weight = (const float*)d_in[2];
    const float* bias         = (const float*)d_in[3];
    const float* tau          = (const float*)d_in[4];
    (void)in_sizes; (void)n_in; (void)out_size; (void)ws_size;

    bf16_t* wsw   = (bf16_t*)d_ws;
    bf16_t* winsw = wsw + 65536;

    static bool attr_set = false;
    if (!attr_set) {
        (void)hipFuncSetAttribute((const void*)rnn_kernel,
                                  hipFuncAttributeMaxDynamicSharedMemorySize,
                                  LDS_TOTAL);
        attr_set = true;
    }

    swz_kernel<<<16, 256, 0, stream>>>(weight, input_weight, wsw, winsw);
    rnn_kernel<<<512, 256, LDS_TOTAL, stream>>>(x, bias, tau,
                                                (const bf16x8*)wsw,
                                                (const bf16x8*)winsw,
                                                (float*)d_out);
}